// Round 1
// baseline (1562.411 us; speedup 1.0000x reference)
//
#include <hip/hip_runtime.h>
#include <hip/hip_bf16.h>

#define NN 100000
#define EE 1600000

__device__ __forceinline__ float act_apply(float v, int act) {
  if (act == 1) return 1.0f / (1.0f + expf(-v));
  if (act == 2) return fmaxf(v, 0.0f);
  return v;
}

// ---------------- CSR build ----------------
__global__ void k_count(const int* __restrict__ ei, int* __restrict__ cnt) {
  int e = blockIdx.x * blockDim.x + threadIdx.x;
  if (e < EE) atomicAdd(&cnt[ei[EE + e]], 1);
}

__global__ void k_scan(const int* __restrict__ cnt, int* __restrict__ off,
                       int* __restrict__ cursor, float* __restrict__ dis) {
  __shared__ int sh[1024];
  __shared__ int carry;
  if (threadIdx.x == 0) carry = 0;
  __syncthreads();
  for (int base = 0; base < NN; base += 1024) {
    int i = base + threadIdx.x;
    int v = (i < NN) ? cnt[i] : 0;
    sh[threadIdx.x] = v;
    __syncthreads();
    for (int s = 1; s < 1024; s <<= 1) {
      int t = (threadIdx.x >= s) ? sh[threadIdx.x - s] : 0;
      __syncthreads();
      sh[threadIdx.x] += t;
      __syncthreads();
    }
    if (i < NN) {
      int ex = carry + sh[threadIdx.x] - v;   // exclusive
      off[i] = ex;
      cursor[i] = ex;
      dis[i] = (v > 0) ? rsqrtf((float)v) : 0.0f;
    }
    __syncthreads();
    if (threadIdx.x == 1023) carry += sh[1023];
    __syncthreads();
  }
  if (threadIdx.x == 0) off[NN] = carry;
}

__global__ void k_fill(const int* __restrict__ ei, int* __restrict__ cursor,
                       int* __restrict__ csr_src) {
  int e = blockIdx.x * blockDim.x + threadIdx.x;
  if (e < EE) {
    int d = ei[EE + e];
    int pos = atomicAdd(&cursor[d], 1);
    csr_src[pos] = ei[e];
  }
}

// ---------------- gather / propagate ----------------
// MODE 0: SAGE mean: r = sum(h[src]) / max(cnt,1)
// MODE 1: TAG norm:  r = dis[i] * sum(dis[src]*h[src])
// then r += add[i], r += bias[t], activation.
template<int D, int G, int MODE, int ACT, bool HAS_ADD, bool HAS_BIAS>
__global__ void k_gather(const float* __restrict__ h, int hs,
                         const float* __restrict__ add, int as,
                         const float* __restrict__ bias,
                         const int* __restrict__ csr_off,
                         const int* __restrict__ csr_src,
                         const float* __restrict__ dis,
                         float* __restrict__ out, int os) {
  const int gpb = 256 / G;
  int gi = blockIdx.x * gpb + threadIdx.x / G;
  int t = threadIdx.x % G;
  if (gi >= NN) return;
  int s = csr_off[gi], e = csr_off[gi + 1];
  float acc = 0.0f;
  for (int p = s; p < e; ++p) {
    int src = csr_src[p];
    if (t < D) {
      float v = h[(long)src * hs + t];
      if (MODE == 1) v *= dis[src];
      acc += v;
    }
  }
  if (t < D) {
    float r;
    if (MODE == 0) {
      int c = e - s;
      r = acc / (float)(c > 0 ? c : 1);
    } else {
      r = acc * dis[gi];
    }
    if (HAS_ADD) r += add[(long)gi * as + t];
    if (HAS_BIAS) r += bias[t];
    out[(long)gi * os + t] = act_apply(r, ACT);
  }
}

// ---------------- SAGE fused GEMM: out = act([A1||A2] @ [W1||W2]^T + b) ----------------
template<int K1, int K2>
__global__ __launch_bounds__(256) void k_sage_mm(
    const float* __restrict__ A1, const float* __restrict__ A2,
    const float* __restrict__ W1, const float* __restrict__ W2,  // [128][K1],[128][K2]
    const float* __restrict__ bias, float* __restrict__ out, int act) {
  constexpr int K = K1 + K2;
  constexpr int BM = 64;
  constexpr int BK = 32;
  __shared__ float Ash[BK][BM];    // [k][m]
  __shared__ float Wsh[BK][128];   // [k][o]
  int m0 = blockIdx.x * BM;
  int tid = threadIdx.x;
  int tx = tid & 15, ty = tid >> 4;
  int tm = ty * 4;   // 4 nodes
  int to = tx * 8;   // 8 outputs
  float acc[4][8] = {};
  for (int k0 = 0; k0 < K; k0 += BK) {
    {
      int mm = tid % BM, kb = tid / BM;  // kb 0..3
      #pragma unroll
      for (int it = 0; it < BK / 4; ++it) {
        int kk = kb + 4 * it;
        int gk = k0 + kk, gm = m0 + mm;
        float v = 0.0f;
        if (gm < NN && gk < K)
          v = (gk < K1) ? A1[(long)gm * K1 + gk] : A2[(long)gm * K2 + (gk - K1)];
        Ash[kk][mm] = v;
      }
    }
    {
      int oo = tid % 128, kb = tid / 128;  // kb 0..1
      #pragma unroll
      for (int it = 0; it < BK / 2; ++it) {
        int kk = kb + 2 * it;
        int gk = k0 + kk;
        float v = 0.0f;
        if (gk < K)
          v = (gk < K1) ? W1[oo * K1 + gk] : W2[oo * K2 + (gk - K1)];
        Wsh[kk][oo] = v;
      }
    }
    __syncthreads();
    #pragma unroll
    for (int kk = 0; kk < BK; ++kk) {
      float4 av  = *reinterpret_cast<const float4*>(&Ash[kk][tm]);
      float4 wv0 = *reinterpret_cast<const float4*>(&Wsh[kk][to]);
      float4 wv1 = *reinterpret_cast<const float4*>(&Wsh[kk][to + 4]);
      float a[4] = {av.x, av.y, av.z, av.w};
      float w[8] = {wv0.x, wv0.y, wv0.z, wv0.w, wv1.x, wv1.y, wv1.z, wv1.w};
      #pragma unroll
      for (int i2 = 0; i2 < 4; ++i2)
        #pragma unroll
        for (int j = 0; j < 8; ++j)
          acc[i2][j] += a[i2] * w[j];
    }
    __syncthreads();
  }
  #pragma unroll
  for (int i2 = 0; i2 < 4; ++i2) {
    int gm = m0 + tm + i2;
    if (gm >= NN) continue;
    float4 o0, o1;
    o0.x = act_apply(acc[i2][0] + bias[to + 0], act);
    o0.y = act_apply(acc[i2][1] + bias[to + 1], act);
    o0.z = act_apply(acc[i2][2] + bias[to + 2], act);
    o0.w = act_apply(acc[i2][3] + bias[to + 3], act);
    o1.x = act_apply(acc[i2][4] + bias[to + 4], act);
    o1.y = act_apply(acc[i2][5] + bias[to + 5], act);
    o1.z = act_apply(acc[i2][6] + bias[to + 6], act);
    o1.w = act_apply(acc[i2][7] + bias[to + 7], act);
    *reinterpret_cast<float4*>(&out[(long)gm * 128 + to])     = o0;
    *reinterpret_cast<float4*>(&out[(long)gm * 128 + to + 4]) = o1;
  }
}

// ---------------- TAG P-precompute: P[i][k*NO+o] = sum_j A[i][j]*w[o][KIN*k+j] ----------------
template<int KIN, int NH, int NO>
__global__ void k_tagP(const float* __restrict__ A, int as,
                       const float* __restrict__ w, float* __restrict__ out) {
  int i = blockIdx.x * blockDim.x + threadIdx.x;
  if (i >= NN) return;
  float a[KIN];
  #pragma unroll
  for (int j = 0; j < KIN; ++j) a[j] = A[(long)i * as + j];
  #pragma unroll
  for (int k = 0; k < NH; ++k) {
    #pragma unroll
    for (int o = 0; o < NO; ++o) {
      float s = 0.0f;
      #pragma unroll
      for (int j = 0; j < KIN; ++j) s += a[j] * w[o * (KIN * NH) + k * KIN + j];
      out[(long)i * (NH * NO) + k * NO + o] = s;
    }
  }
}

// SAGE3 projections: p = x1b @ wl3^T, q = x1b @ wr3^T  (both [N,1])
__global__ void k_proj2(const float* __restrict__ A, const float* __restrict__ w1,
                        const float* __restrict__ w2, float* __restrict__ P,
                        float* __restrict__ Q) {
  int i = blockIdx.x * blockDim.x + threadIdx.x;
  if (i >= NN) return;
  const float4* a4 = reinterpret_cast<const float4*>(A + (long)i * 128);
  float s1 = 0.0f, s2 = 0.0f;
  #pragma unroll
  for (int k = 0; k < 32; ++k) {
    float4 v = a4[k];
    s1 += v.x * w1[4 * k] + v.y * w1[4 * k + 1] + v.z * w1[4 * k + 2] + v.w * w1[4 * k + 3];
    s2 += v.x * w2[4 * k] + v.y * w2[4 * k + 1] + v.z * w2[4 * k + 2] + v.w * w2[4 * k + 3];
  }
  P[i] = s1;
  Q[i] = s2;
}

__global__ void k_final(const float* __restrict__ x1, const float* __restrict__ x2,
                        const float* __restrict__ x3, const float* __restrict__ lw,
                        const float* __restrict__ lb, float* __restrict__ out) {
  int i = blockIdx.x * blockDim.x + threadIdx.x;
  if (i >= NN) return;
  float v = x1[i] * lw[0] + x2[i] * lw[1] + x3[i] * lw[2] + lb[0];
  out[i] = fmaxf(v, 0.0f);
}

extern "C" void kernel_launch(void* const* d_in, const int* in_sizes, int n_in,
                              void* d_out, int out_size, void* d_ws, size_t ws_size,
                              hipStream_t stream) {
  const float* x    = (const float*)d_in[0];
  const int*   ei   = (const int*)d_in[1];
  const float* s1wl = (const float*)d_in[2];
  const float* s1wr = (const float*)d_in[3];
  const float* s1b  = (const float*)d_in[4];
  const float* s2wl = (const float*)d_in[5];
  const float* s2wr = (const float*)d_in[6];
  const float* s2b  = (const float*)d_in[7];
  const float* s3wl = (const float*)d_in[8];
  const float* s3wr = (const float*)d_in[9];
  const float* s3b  = (const float*)d_in[10];
  const float* t1aw = (const float*)d_in[11];
  const float* t1ab = (const float*)d_in[12];
  const float* t2aw = (const float*)d_in[13];
  const float* t2ab = (const float*)d_in[14];
  const float* t1bw = (const float*)d_in[15];
  const float* t1bb = (const float*)d_in[16];
  const float* t2bw = (const float*)d_in[17];
  const float* t2bb = (const float*)d_in[18];
  const float* lw   = (const float*)d_in[19];
  const float* lb   = (const float*)d_in[20];
  float* out = (float*)d_out;

  char* basep = (char*)d_ws;
  size_t off = 0;
  auto alloc = [&](size_t bytes) -> void* {
    void* ptr = basep + off;
    off = (off + bytes + 255) & ~(size_t)255;
    return ptr;
  };
  int*   cnt     = (int*)alloc((size_t)NN * 4);
  int*   csr_off = (int*)alloc((size_t)(NN + 1) * 4);
  int*   cursor  = (int*)alloc((size_t)NN * 4);
  float* dis     = (float*)alloc((size_t)NN * 4);
  int*   csr_src = (int*)alloc((size_t)EE * 4);
  float* x1s     = (float*)alloc((size_t)NN * 4);
  float* x2s     = (float*)alloc((size_t)NN * 4);
  float* x3s     = (float*)alloc((size_t)NN * 4);
  float* pp      = (float*)alloc((size_t)NN * 4);
  float* qq      = (float*)alloc((size_t)NN * 4);
  float* u1      = (float*)alloc((size_t)NN * 4);
  float* u2      = (float*)alloc((size_t)NN * 4);
  float* mean11  = (float*)alloc((size_t)NN * 11 * 4);
  float* x1a     = (float*)alloc((size_t)NN * 128 * 4);
  float* mean128 = (float*)alloc((size_t)NN * 128 * 4);
  float* x1b     = (float*)alloc((size_t)NN * 128 * 4);

  // TAG buffers reuse the big SAGE regions (TAG phase runs after SAGE phase).
  float* Pa  = x1a;                       // [N,32]
  float* za  = x1a + (size_t)NN * 32;     // [N,8]
  float* zb  = za + (size_t)NN * 8;       // [N,8]
  float* x2a = zb + (size_t)NN * 8;       // [N,8]
  float* P2  = x2a + (size_t)NN * 8;      // [N,4]
  float* Pb  = mean128;                   // [N,56]
  float* x3a = mean128 + (size_t)NN * 56; // [N,8]
  float* P2b = x3a + (size_t)NN * 8;      // [N,7]

  // ---- CSR build ----
  hipMemsetAsync(cnt, 0, (size_t)NN * 4, stream);
  k_count<<<(EE + 255) / 256, 256, 0, stream>>>(ei, cnt);
  k_scan<<<1, 1024, 0, stream>>>(cnt, csr_off, cursor, dis);
  k_fill<<<(EE + 255) / 256, 256, 0, stream>>>(ei, cursor, csr_src);

  // ---- SAGE chain ----
  k_gather<11, 16, 0, 0, false, false><<<(NN + 15) / 16, 256, 0, stream>>>(
      x, 11, nullptr, 0, nullptr, csr_off, csr_src, dis, mean11, 11);
  k_sage_mm<11, 11><<<(NN + 63) / 64, 256, 0, stream>>>(mean11, x, s1wl, s1wr, s1b, x1a, 1);
  k_gather<128, 128, 0, 0, false, false><<<(NN + 1) / 2, 256, 0, stream>>>(
      x1a, 128, nullptr, 0, nullptr, csr_off, csr_src, dis, mean128, 128);
  k_sage_mm<128, 128><<<(NN + 63) / 64, 256, 0, stream>>>(mean128, x1a, s2wl, s2wr, s2b, x1b, 1);
  k_proj2<<<(NN + 255) / 256, 256, 0, stream>>>(x1b, s3wl, s3wr, pp, qq);
  k_gather<1, 1, 0, 2, true, true><<<(NN + 255) / 256, 256, 0, stream>>>(
      pp, 1, qq, 1, s3b, csr_off, csr_src, dis, x1s, 1);

  // ---- TAG chain a (K=3) ----
  k_tagP<11, 4, 8><<<(NN + 255) / 256, 256, 0, stream>>>(x, 11, t1aw, Pa);
  k_gather<8, 8, 1, 0, true, false><<<(NN + 31) / 32, 256, 0, stream>>>(
      Pa + 24, 32, Pa + 16, 32, nullptr, csr_off, csr_src, dis, za, 8);
  k_gather<8, 8, 1, 0, true, false><<<(NN + 31) / 32, 256, 0, stream>>>(
      za, 8, Pa + 8, 32, nullptr, csr_off, csr_src, dis, zb, 8);
  k_gather<8, 8, 1, 1, true, true><<<(NN + 31) / 32, 256, 0, stream>>>(
      zb, 8, Pa, 32, t1ab, csr_off, csr_src, dis, x2a, 8);
  k_tagP<8, 4, 1><<<(NN + 255) / 256, 256, 0, stream>>>(x2a, 8, t2aw, P2);
  k_gather<1, 1, 1, 0, true, false><<<(NN + 255) / 256, 256, 0, stream>>>(
      P2 + 3, 4, P2 + 2, 4, nullptr, csr_off, csr_src, dis, u1, 1);
  k_gather<1, 1, 1, 0, true, false><<<(NN + 255) / 256, 256, 0, stream>>>(
      u1, 1, P2 + 1, 4, nullptr, csr_off, csr_src, dis, u2, 1);
  k_gather<1, 1, 1, 2, true, true><<<(NN + 255) / 256, 256, 0, stream>>>(
      u2, 1, P2, 4, t2ab, csr_off, csr_src, dis, x2s, 1);

  // ---- TAG chain b (K=6) ----
  k_tagP<11, 7, 8><<<(NN + 255) / 256, 256, 0, stream>>>(x, 11, t1bw, Pb);
  k_gather<8, 8, 1, 0, true, false><<<(NN + 31) / 32, 256, 0, stream>>>(
      Pb + 48, 56, Pb + 40, 56, nullptr, csr_off, csr_src, dis, za, 8);
  k_gather<8, 8, 1, 0, true, false><<<(NN + 31) / 32, 256, 0, stream>>>(
      za, 8, Pb + 32, 56, nullptr, csr_off, csr_src, dis, zb, 8);
  k_gather<8, 8, 1, 0, true, false><<<(NN + 31) / 32, 256, 0, stream>>>(
      zb, 8, Pb + 24, 56, nullptr, csr_off, csr_src, dis, za, 8);
  k_gather<8, 8, 1, 0, true, false><<<(NN + 31) / 32, 256, 0, stream>>>(
      za, 8, Pb + 16, 56, nullptr, csr_off, csr_src, dis, zb, 8);
  k_gather<8, 8, 1, 0, true, false><<<(NN + 31) / 32, 256, 0, stream>>>(
      zb, 8, Pb + 8, 56, nullptr, csr_off, csr_src, dis, za, 8);
  k_gather<8, 8, 1, 1, true, true><<<(NN + 31) / 32, 256, 0, stream>>>(
      za, 8, Pb, 56, t1bb, csr_off, csr_src, dis, x3a, 8);
  k_tagP<8, 7, 1><<<(NN + 255) / 256, 256, 0, stream>>>(x3a, 8, t2bw, P2b);
  k_gather<1, 1, 1, 0, true, false><<<(NN + 255) / 256, 256, 0, stream>>>(
      P2b + 6, 7, P2b + 5, 7, nullptr, csr_off, csr_src, dis, u1, 1);
  k_gather<1, 1, 1, 0, true, false><<<(NN + 255) / 256, 256, 0, stream>>>(
      u1, 1, P2b + 4, 7, nullptr, csr_off, csr_src, dis, u2, 1);
  k_gather<1, 1, 1, 0, true, false><<<(NN + 255) / 256, 256, 0, stream>>>(
      u2, 1, P2b + 3, 7, nullptr, csr_off, csr_src, dis, u1, 1);
  k_gather<1, 1, 1, 0, true, false><<<(NN + 255) / 256, 256, 0, stream>>>(
      u1, 1, P2b + 2, 7, nullptr, csr_off, csr_src, dis, u2, 1);
  k_gather<1, 1, 1, 0, true, false><<<(NN + 255) / 256, 256, 0, stream>>>(
      u2, 1, P2b + 1, 7, nullptr, csr_off, csr_src, dis, u1, 1);
  k_gather<1, 1, 1, 2, true, true><<<(NN + 255) / 256, 256, 0, stream>>>(
      u1, 1, P2b, 7, t2bb, csr_off, csr_src, dis, x3s, 1);

  // ---- final combine ----
  k_final<<<(NN + 255) / 256, 256, 0, stream>>>(x1s, x2s, x3s, lw, lb, out);
}